// Round 4
// baseline (556.244 us; speedup 1.0000x reference)
//
#include <hip/hip_runtime.h>
#include <hip/hip_bf16.h>

#define B_  2048
#define L_  200
#define D_  128
#define H0_ 80
#define H1_ 40
#define BPB 4              // batches per block, grid 512 = 2 blocks/CU, all resident
#define NTILE 13           // 16-row score tiles per batch (208 rows, 8 pad)

// ws layout (shorts): Bg[80][256] @0 | w1t[48][96] @20480 | w0p[128][84] @25088
#define WS_BG  0
#define WS_W1T 20480
#define WS_W0P 25088
#define WS_TOT 35840

typedef __attribute__((ext_vector_type(8))) short short8;
typedef __attribute__((ext_vector_type(4))) float floatx4;

__device__ __forceinline__ short f2bf(float f) {
    unsigned u = __float_as_uint(f);
    u += 0x7fffu + ((u >> 16) & 1u);   // round-to-nearest-even
    return (short)(u >> 16);
}
__device__ __forceinline__ float bf2f(short s) {
    return __uint_as_float(((unsigned)(unsigned short)s) << 16);
}

// ---------------- prep: pure weight transform, one pass ---------------------
// feat@W0 = hist@(W0a+W0c) + (hist.*tgt)@W0d + [tgt@(W0b-W0c)+b0]
__global__ __launch_bounds__(256) void prep_kernel(
    const float* __restrict__ W0, const float* __restrict__ W1,
    short* __restrict__ ws)
{
    for (int i = blockIdx.x * 256 + threadIdx.x; i < WS_TOT; i += 64 * 256) {
        short v;
        if (i < WS_W1T) {                       // Bg[h][k]: k<128 W0a+W0c, k>=128 W0d
            int h = i >> 8, k = i & 255;
            float x = (k < 128) ? (W0[(size_t)k * H0_ + h] + W0[(size_t)(256 + k) * H0_ + h])
                                : W0[(size_t)(384 + (k - 128)) * H0_ + h];
            v = f2bf(x);
        } else if (i < WS_W0P) {                // w1t[n][k] 48x96, zero-padded
            int j = i - WS_W1T;
            int n = j / 96, k = j - n * 96;
            v = (n < H1_ && k < H0_) ? f2bf(W1[(size_t)k * H1_ + n]) : (short)0;
        } else {                                // w0p[d][h] 128x84 = bf16(W0b-W0c), padded
            int j = i - WS_W0P;
            int d = j / 84, h = j - d * 84;
            v = (h < H0_) ? f2bf(W0[(size_t)(128 + d) * H0_ + h] - W0[(size_t)(256 + d) * H0_ + h])
                          : (short)0;
        }
        ws[i] = v;
    }
}

// ---------------- fused: reg-resident W0eff GEMM + softmax + wsum -----------
// W0eff[b][d][h] = Bg1[h][d] + tgt[b][d]*Bg2[h][d]   (layer-0 K=128)
// B-fragments of W0eff live in registers per wave; score phase is barrier-free.
__global__ __launch_bounds__(256, 2) void fused_kernel(
    const float* __restrict__ hist, const float* __restrict__ tgt,
    const int* __restrict__ mask, const short* __restrict__ ws,
    const float* __restrict__ b0p, const float* __restrict__ b1,
    const float* __restrict__ W2, const float* __restrict__ b2,
    float* __restrict__ out)
{
    __shared__ __align__(16) short h0t[4][16][104];  // 13312 B, wave-private
    __shared__ float tgs4[BPB][D_];                  // 2048 B
    __shared__ float beffs[BPB][H0_];                // 1280 B
    __shared__ float scores4[BPB][208];              // 3328 B
    __shared__ float red[8];
    __shared__ float p0[D_], p1[D_];                 // 1024 B
    // total ~21 KB; occupancy limited by grid (2 blocks/CU), VGPR cap 256

    const int tid = threadIdx.x;
    const int wave = tid >> 6, lane = tid & 63;
    const int col = lane & 15, quad = lane >> 4;
    const int bbase = blockIdx.x * BPB;

    // ---- prologue: stage tgt rows, zero h0t k-tail, hoist w1 frags ----
    for (int i = tid; i < BPB * D_; i += 256)
        tgs4[i >> 7][i & 127] = tgt[(size_t)(bbase + (i >> 7)) * D_ + (i & 127)];
    if (tid < 192) {                                  // zero h0t cols 80..103
        int w = tid / 48, rem = tid % 48, row = rem / 3, c = 80 + (rem % 3) * 8;
        *(short8*)&h0t[w][row][c] = (short8)0;
    }
    short8 w1f[3][3];
    #pragma unroll
    for (int ks = 0; ks < 3; ++ks)
        #pragma unroll
        for (int nt = 0; nt < 3; ++nt)
            w1f[ks][nt] = *(const short8*)(ws + WS_W1T + (nt * 16 + col) * 96 + ks * 32 + quad * 8);
    float b1r[3], w2r[3];
    #pragma unroll
    for (int nt = 0; nt < 3; ++nt) {
        int h = nt * 16 + col;
        b1r[nt] = (h < H1_) ? b1[h] : 0.f;
        w2r[nt] = (h < H1_) ? W2[h] : 0.f;
    }
    const float b2v = b2[0];
    __syncthreads();                                  // tgs4 ready

    // ---- beff[bb][h] = b0[h] + tgt[bb] . (W0b-W0c)[:,h]  (w0p L2-hot) ----
    for (int p = tid; p < BPB * H0_; p += 256) {
        int bb = p / H0_, h = p - bb * H0_;
        float s = 0.f;
        #pragma unroll 8
        for (int d = 0; d < D_; ++d)
            s += tgs4[bb][d] * bf2f(ws[WS_W0P + d * 84 + h]);
        beffs[bb][h] = b0p[h] + s;
    }
    __syncthreads();                                  // beffs ready; no more barriers until tail

    // ---- score phase: per batch, W0eff B-frags in regs, A prefetched ----
    for (int bb = 0; bb < BPB; ++bb) {
        const int b = bbase + bb;
        int t = (wave + bb) & 3;                      // rotate extra tile -> 13 tiles/wave total

        // issue first A-tile load early (overlaps w0e build)
        floatx4 A[8];
        {
            const int l = t * 16 + col;
            const int lc = (l < L_) ? l : (L_ - 1);
            const float* ap = hist + ((size_t)b * L_ + lc) * D_ + quad * 8;
            #pragma unroll
            for (int u = 0; u < 8; ++u)
                A[u] = *(const floatx4*)(ap + (u >> 1) * 32 + (u & 1) * 4);
        }

        // build this lane's layer-0 B-frags: w0e[ks][nt] (80 VGPRs)
        short8 w0e[4][5];
        #pragma unroll
        for (int ks = 0; ks < 4; ++ks) {
            const int d0 = ks * 32 + quad * 8;
            floatx4 t0 = *(const floatx4*)&tgs4[bb][d0];
            floatx4 t1 = *(const floatx4*)&tgs4[bb][d0 + 4];
            #pragma unroll
            for (int nt = 0; nt < 5; ++nt) {
                const int h = nt * 16 + col;
                short8 wa = *(const short8*)(ws + WS_BG + h * 256 + d0);
                short8 wd = *(const short8*)(ws + WS_BG + h * 256 + 128 + d0);
                short8 o;
                #pragma unroll
                for (int j = 0; j < 4; ++j) o[j] = f2bf(bf2f(wa[j]) + t0[j] * bf2f(wd[j]));
                #pragma unroll
                for (int j = 4; j < 8; ++j) o[j] = f2bf(bf2f(wa[j]) + t1[j - 4] * bf2f(wd[j]));
                w0e[ks][nt] = o;
            }
        }

        while (t < NTILE) {
            const int tn = t + 4;
            // prefetch next tile's A while computing this one
            floatx4 An[8];
            if (tn < NTILE) {
                const int l = tn * 16 + col;
                const int lc = (l < L_) ? l : (L_ - 1);
                const float* ap = hist + ((size_t)b * L_ + lc) * D_ + quad * 8;
                #pragma unroll
                for (int u = 0; u < 8; ++u)
                    An[u] = *(const floatx4*)(ap + (u >> 1) * 32 + (u & 1) * 4);
            }

            // pack A-frags (hist only; K=128)
            short8 ah[4];
            #pragma unroll
            for (int ks = 0; ks < 4; ++ks) {
                short8 h8;
                #pragma unroll
                for (int j = 0; j < 8; ++j) h8[j] = f2bf(A[2 * ks + (j >> 2)][j & 3]);
                ah[ks] = h8;
            }

            // layer 0: K=128, B from registers
            floatx4 c0[5];
            #pragma unroll
            for (int nt = 0; nt < 5; ++nt) c0[nt] = (floatx4)0.f;
            #pragma unroll
            for (int ks = 0; ks < 4; ++ks)
                #pragma unroll
                for (int nt = 0; nt < 5; ++nt)
                    c0[nt] = __builtin_amdgcn_mfma_f32_16x16x32_bf16(ah[ks], w0e[ks][nt], c0[nt], 0, 0, 0);

            // bias+relu -> wave-private h0 tile
            #pragma unroll
            for (int nt = 0; nt < 5; ++nt) {
                float be = beffs[bb][nt * 16 + col];
                #pragma unroll
                for (int r = 0; r < 4; ++r) {
                    float v = c0[nt][r] + be;
                    v = v > 0.f ? v : 0.f;
                    h0t[wave][quad * 4 + r][nt * 16 + col] = f2bf(v);
                }
            }

            // layer 1 (w1 frags in regs)
            floatx4 c1[3];
            #pragma unroll
            for (int nt = 0; nt < 3; ++nt) c1[nt] = (floatx4)0.f;
            #pragma unroll
            for (int ks = 0; ks < 3; ++ks) {
                short8 a1 = *(const short8*)&h0t[wave][col][ks * 32 + quad * 8];
                #pragma unroll
                for (int nt = 0; nt < 3; ++nt)
                    c1[nt] = __builtin_amdgcn_mfma_f32_16x16x32_bf16(a1, w1f[ks][nt], c1[nt], 0, 0, 0);
            }

            // layer 2 + 16-lane reduce -> LDS scores
            float s4[4] = {0.f, 0.f, 0.f, 0.f};
            #pragma unroll
            for (int nt = 0; nt < 3; ++nt)
                #pragma unroll
                for (int r = 0; r < 4; ++r) {
                    float v = c1[nt][r] + b1r[nt];
                    v = v > 0.f ? v : 0.f;
                    s4[r] += v * w2r[nt];
                }
            #pragma unroll
            for (int r = 0; r < 4; ++r) {
                s4[r] += __shfl_xor(s4[r], 1, 16);
                s4[r] += __shfl_xor(s4[r], 2, 16);
                s4[r] += __shfl_xor(s4[r], 4, 16);
                s4[r] += __shfl_xor(s4[r], 8, 16);
            }
            if (col == 0) {
                #pragma unroll
                for (int r = 0; r < 4; ++r)
                    scores4[bb][t * 16 + quad * 4 + r] = s4[r] + b2v;
            }

            if (tn < NTILE) {
                #pragma unroll
                for (int u = 0; u < 8; ++u) A[u] = An[u];
            }
            t = tn;
        }
    }
    __syncthreads();

    // ---- tail (round-2 proven): per-batch softmax + wsum, hist L3-hot ----
    for (int bb = 0; bb < BPB; ++bb) {
        const int b = bbase + bb;

        float sc = -3.0e38f;
        if (tid < L_) {
            sc = scores4[bb][tid];
            if (mask[(size_t)b * L_ + tid] == 0) sc -= 1e9f;
        }
        float m = sc;
        #pragma unroll
        for (int off = 32; off >= 1; off >>= 1) m = fmaxf(m, __shfl_xor(m, off, 64));
        if (lane == 0) red[wave] = m;
        __syncthreads();
        m = fmaxf(fmaxf(red[0], red[1]), fmaxf(red[2], red[3]));
        float e = (tid < L_) ? __expf(sc - m) : 0.f;
        float s = e;
        #pragma unroll
        for (int off = 32; off >= 1; off >>= 1) s += __shfl_xor(s, off, 64);
        if (lane == 0) red[4 + wave] = s;
        __syncthreads();
        s = red[4] + red[5] + red[6] + red[7];
        float av = e * (1.0f / s);
        if (tid < L_) {
            scores4[bb][tid] = av;                                   // reuse as attn weights
            out[(size_t)B_ * D_ + (size_t)b * L_ + tid] = av;
        }
        __syncthreads();

        const int half = tid >> 7, d = tid & 127;
        const float* hb = hist + ((size_t)b * L_ + half * 100) * D_ + d;
        float acc = 0.f;
        #pragma unroll 25
        for (int l = 0; l < 100; ++l)
            acc = fmaf(scores4[bb][half * 100 + l], hb[(size_t)l * D_], acc);
        if (half) p1[d] = acc; else p0[d] = acc;
        __syncthreads();
        if (tid < D_) out[(size_t)b * D_ + tid] = p0[tid] + p1[tid];
    }
}

extern "C" void kernel_launch(void* const* d_in, const int* in_sizes, int n_in,
                              void* d_out, int out_size, void* d_ws, size_t ws_size,
                              hipStream_t stream) {
    const float* hist = (const float*)d_in[0];
    const float* tgt  = (const float*)d_in[1];
    const int*   mask = (const int*)d_in[2];
    const float* W0   = (const float*)d_in[3];
    const float* b0   = (const float*)d_in[4];
    const float* W1   = (const float*)d_in[5];
    const float* b1   = (const float*)d_in[6];
    const float* W2   = (const float*)d_in[7];
    const float* b2   = (const float*)d_in[8];

    short* ws = (short*)d_ws;

    prep_kernel<<<64, 256, 0, stream>>>(W0, W1, ws);
    fused_kernel<<<B_ / BPB, 256, 0, stream>>>(hist, tgt, mask, ws, b0, b1, W2, b2,
                                               (float*)d_out);
}

// Round 5
// 332.407 us; speedup vs baseline: 1.6734x; 1.6734x over previous
//
#include <hip/hip_runtime.h>
#include <hip/hip_bf16.h>

#define B_  2048
#define L_  200
#define D_  128
#define H0_ 80
#define H1_ 40
#define BPB 2              // batches per block -> grid 1024 = 4 blocks/CU
#define NTILE 13           // 16-row score tiles per batch (208 rows, 8 pad)

// ws layout (shorts): Bg[80][256] @0 | w1t[48][96] @20480 | w0p[128][84] @25088
#define WS_BG  0
#define WS_W1T 20480
#define WS_W0P 25088
#define WS_TOT 35840

typedef __attribute__((ext_vector_type(8))) short short8;
typedef __attribute__((ext_vector_type(4))) float floatx4;
typedef __attribute__((ext_vector_type(2))) float floatx2;

__device__ __forceinline__ short f2bf(float f) {
    unsigned u = __float_as_uint(f);
    u += 0x7fffu + ((u >> 16) & 1u);   // round-to-nearest-even
    return (short)(u >> 16);
}
__device__ __forceinline__ float bf2f(short s) {
    return __uint_as_float(((unsigned)(unsigned short)s) << 16);
}

// ---------------- prep: pure weight transform, one pass ---------------------
// feat@W0 = hist@(W0a+W0c) + (hist.*tgt)@W0d + [tgt@(W0b-W0c)+b0]
__global__ __launch_bounds__(256) void prep_kernel(
    const float* __restrict__ W0, const float* __restrict__ W1,
    short* __restrict__ ws)
{
    for (int i = blockIdx.x * 256 + threadIdx.x; i < WS_TOT; i += 64 * 256) {
        short v;
        if (i < WS_W1T) {                       // Bg[h][k]: k<128 W0a+W0c, k>=128 W0d
            int h = i >> 8, k = i & 255;
            float x = (k < 128) ? (W0[(size_t)k * H0_ + h] + W0[(size_t)(256 + k) * H0_ + h])
                                : W0[(size_t)(384 + (k - 128)) * H0_ + h];
            v = f2bf(x);
        } else if (i < WS_W0P) {                // w1t[n][k] 48x96, zero-padded
            int j = i - WS_W1T;
            int n = j / 96, k = j - n * 96;
            v = (n < H1_ && k < H0_) ? f2bf(W1[(size_t)k * H1_ + n]) : (short)0;
        } else {                                // w0p[d][h] 128x84 = bf16(W0b-W0c), padded
            int j = i - WS_W0P;
            int d = j / 84, h = j - d * 84;
            v = (h < H0_) ? f2bf(W0[(size_t)(128 + d) * H0_ + h] - W0[(size_t)(256 + d) * H0_ + h])
                          : (short)0;
        }
        ws[i] = v;
    }
}

// ---------------- fused: per-batch W0eff (LDS) GEMM + softmax + wsum --------
// W0eff[b][d][h] = Bg1[h][d] + tgt[b][d]*Bg2[h][d]   (layer-0 K=128)
// LDS 37.6 KB -> 4 blocks/CU; VGPR target 128 -> 4 waves/SIMD -> 16 waves/CU.
__global__ __launch_bounds__(256, 2) void fused_kernel(
    const float* __restrict__ hist, const float* __restrict__ tgt,
    const int* __restrict__ mask, const short* __restrict__ ws,
    const float* __restrict__ b0p, const float* __restrict__ b1,
    const float* __restrict__ W2, const float* __restrict__ b2,
    float* __restrict__ out)
{
    __shared__ __align__(16) short wbuf[10752];      // w0p[128][84] then W0eff[80][132]
    __shared__ __align__(16) short h0t[4][16][100];  // 12800 B; tail: pw[4][128]+attn_w[2][200] f32
    __shared__ float tgs4[BPB][D_];                  // 1024 B
    __shared__ float beffs[BPB][H0_];                // 640 B
    __shared__ float scores4[BPB][208];              // 1664 B
    // total 37632 B

    const int tid = threadIdx.x;
    const int wave = tid >> 6, lane = tid & 63;
    const int col = lane & 15, quad = lane >> 4;
    const int bbase = blockIdx.x * BPB;

    // ---- prologue: stage w0p + tgt rows, zero h0t k-tail, hoist w1 frags ----
    for (int i = tid; i < 1344; i += 256)                 // w0p: 10752 shorts
        *(short8*)(wbuf + i * 8) = *(const short8*)(ws + WS_W0P + i * 8);
    for (int i = tid; i < BPB * D_; i += 256)
        tgs4[i >> 7][i & 127] = tgt[(size_t)(bbase + (i >> 7)) * D_ + (i & 127)];
    if (tid < 128) {                                      // zero h0t cols 80..95
        int w = tid >> 5, row = (tid >> 1) & 15, c = 80 + (tid & 1) * 8;
        *(short8*)&h0t[w][row][c] = (short8)0;
    }
    short8 w1f[3][3];
    #pragma unroll
    for (int ks = 0; ks < 3; ++ks)
        #pragma unroll
        for (int nt = 0; nt < 3; ++nt)
            w1f[ks][nt] = *(const short8*)(ws + WS_W1T + (nt * 16 + col) * 96 + ks * 32 + quad * 8);
    float b1r[3], w2r[3];
    #pragma unroll
    for (int nt = 0; nt < 3; ++nt) {
        int h = nt * 16 + col;
        b1r[nt] = (h < H1_) ? b1[h] : 0.f;
        w2r[nt] = (h < H1_) ? W2[h] : 0.f;
    }
    const float b2v = b2[0];
    __syncthreads();

    // ---- beff: beff[bb][h] = b0[h] + tgt[bb] . (W0b-W0c)[:,h] ----
    if (tid < 160) {
        int bb = tid >= 80 ? 1 : 0, h = tid - bb * 80;
        float s = 0.f;
        #pragma unroll 8
        for (int d = 0; d < D_; ++d) s += tgs4[bb][d] * bf2f(wbuf[d * 84 + h]);
        beffs[bb][h] = b0p[h] + s;
    }
    __syncthreads();                                      // w0p region now free

    // ---- per-batch: build W0eff in LDS, then 13 score tiles (K=128) ----
    for (int bb = 0; bb < BPB; ++bb) {
        for (int i = tid; i < 1280; i += 256) {           // 80 rows x 16 chunks of 8
            int h = i >> 4, d0 = (i & 15) * 8;
            short8 wa = *(const short8*)(ws + WS_BG + h * 256 + d0);
            short8 wd = *(const short8*)(ws + WS_BG + h * 256 + 128 + d0);
            floatx4 t0 = *(const floatx4*)&tgs4[bb][d0];
            floatx4 t1 = *(const floatx4*)&tgs4[bb][d0 + 4];
            short8 o;
            #pragma unroll
            for (int j = 0; j < 4; ++j) o[j] = f2bf(bf2f(wa[j]) + t0[j] * bf2f(wd[j]));
            #pragma unroll
            for (int j = 4; j < 8; ++j) o[j] = f2bf(bf2f(wa[j]) + t1[j - 4] * bf2f(wd[j]));
            *(short8*)(wbuf + h * 132 + d0) = o;
        }
        __syncthreads();

        const int b = bbase + bb;
        for (int t = (wave + bb) & 3; t < NTILE; t += 4) {
            const int l = t * 16 + col;
            const int lc = (l < L_) ? l : (L_ - 1);       // clamp pad rows (masked later)
            const float* ap = hist + ((size_t)b * L_ + lc) * D_ + quad * 8;

            floatx4 A[8];
            #pragma unroll
            for (int u = 0; u < 8; ++u)
                A[u] = *(const floatx4*)(ap + (u >> 1) * 32 + (u & 1) * 4);

            short8 ah[4];
            #pragma unroll
            for (int ks = 0; ks < 4; ++ks) {
                short8 h8;
                #pragma unroll
                for (int j = 0; j < 8; ++j) h8[j] = f2bf(A[2 * ks + (j >> 2)][j & 3]);
                ah[ks] = h8;
            }

            // layer 0: K=128 against per-batch W0eff (B-frags from LDS)
            floatx4 c0[5];
            #pragma unroll
            for (int nt = 0; nt < 5; ++nt) c0[nt] = (floatx4)0.f;
            #pragma unroll
            for (int ks = 0; ks < 4; ++ks)
                #pragma unroll
                for (int nt = 0; nt < 5; ++nt) {
                    short8 bfr = *(const short8*)(wbuf + (nt * 16 + col) * 132 + ks * 32 + quad * 8);
                    c0[nt] = __builtin_amdgcn_mfma_f32_16x16x32_bf16(ah[ks], bfr, c0[nt], 0, 0, 0);
                }

            // bias+relu -> wave-private h0 tile
            #pragma unroll
            for (int nt = 0; nt < 5; ++nt) {
                float be = beffs[bb][nt * 16 + col];
                #pragma unroll
                for (int r = 0; r < 4; ++r) {
                    float v = c0[nt][r] + be;
                    v = v > 0.f ? v : 0.f;
                    h0t[wave][quad * 4 + r][nt * 16 + col] = f2bf(v);
                }
            }

            // layer 1 (w1 frags in regs)
            floatx4 c1[3];
            #pragma unroll
            for (int nt = 0; nt < 3; ++nt) c1[nt] = (floatx4)0.f;
            #pragma unroll
            for (int ks = 0; ks < 3; ++ks) {
                short8 a1 = *(const short8*)&h0t[wave][col][ks * 32 + quad * 8];
                #pragma unroll
                for (int nt = 0; nt < 3; ++nt)
                    c1[nt] = __builtin_amdgcn_mfma_f32_16x16x32_bf16(a1, w1f[ks][nt], c1[nt], 0, 0, 0);
            }

            // layer 2 + 16-lane reduce -> LDS scores
            float s4[4] = {0.f, 0.f, 0.f, 0.f};
            #pragma unroll
            for (int nt = 0; nt < 3; ++nt)
                #pragma unroll
                for (int r = 0; r < 4; ++r) {
                    float v = c1[nt][r] + b1r[nt];
                    v = v > 0.f ? v : 0.f;
                    s4[r] += v * w2r[nt];
                }
            #pragma unroll
            for (int r = 0; r < 4; ++r) {
                s4[r] += __shfl_xor(s4[r], 1, 16);
                s4[r] += __shfl_xor(s4[r], 2, 16);
                s4[r] += __shfl_xor(s4[r], 4, 16);
                s4[r] += __shfl_xor(s4[r], 8, 16);
            }
            if (col == 0) {
                #pragma unroll
                for (int r = 0; r < 4; ++r)
                    scores4[bb][t * 16 + quad * 4 + r] = s4[r] + b2v;
            }
        }
        __syncthreads();                                  // scores done / W0eff free
    }

    // ---- tail: one batch per wave-pair, softmax in-wave, then wsum ----
    float* pw = (float*)&h0t[0][0][0];                    // [4][128]
    float* attn_w = pw + 4 * 128;                         // [2][200]
    {
        const int bb = wave >> 1, b = bbase + bb, half = wave & 1;
        float sc[4], e[4];
        float m = -3.0e38f;
        #pragma unroll
        for (int j = 0; j < 4; ++j) {
            int idx = lane + 64 * j;
            if (idx < L_) {
                float v = scores4[bb][idx];
                if (mask[(size_t)b * L_ + idx] == 0) v -= 1e9f;
                sc[j] = v;
                m = fmaxf(m, v);
            } else sc[j] = -3.0e38f;
        }
        #pragma unroll
        for (int off = 32; off >= 1; off >>= 1) m = fmaxf(m, __shfl_xor(m, off, 64));
        float s = 0.f;
        #pragma unroll
        for (int j = 0; j < 4; ++j) {
            int idx = lane + 64 * j;
            e[j] = (idx < L_) ? __expf(sc[j] - m) : 0.f;
            s += e[j];
        }
        #pragma unroll
        for (int off = 32; off >= 1; off >>= 1) s += __shfl_xor(s, off, 64);
        float inv = 1.0f / s;
        if (half == 0) {
            #pragma unroll
            for (int j = 0; j < 4; ++j) {
                int idx = lane + 64 * j;
                if (idx < L_) {
                    float av = e[j] * inv;
                    attn_w[bb * 200 + idx] = av;
                    out[(size_t)B_ * D_ + (size_t)b * L_ + idx] = av;
                }
            }
        }
    }
    __syncthreads();
    {
        const int bb = wave >> 1, b = bbase + bb, half = wave & 1;
        const int d2 = lane * 2;
        const float* hb = hist + ((size_t)b * L_ + half * 100) * D_ + d2;
        float a0 = 0.f, a1 = 0.f;
        #pragma unroll 25
        for (int l = 0; l < 100; ++l) {
            float w = attn_w[bb * 200 + half * 100 + l];
            floatx2 h2 = *(const floatx2*)(hb + (size_t)l * D_);
            a0 = fmaf(w, h2.x, a0);
            a1 = fmaf(w, h2.y, a1);
        }
        *(floatx2*)&pw[wave * 128 + d2] = floatx2{a0, a1};
    }
    __syncthreads();
    {
        int bp = tid >> 7, d = tid & 127;
        out[(size_t)(bbase + bp) * D_ + d] = pw[(bp * 2) * 128 + d] + pw[(bp * 2 + 1) * 128 + d];
    }
}

extern "C" void kernel_launch(void* const* d_in, const int* in_sizes, int n_in,
                              void* d_out, int out_size, void* d_ws, size_t ws_size,
                              hipStream_t stream) {
    const float* hist = (const float*)d_in[0];
    const float* tgt  = (const float*)d_in[1];
    const int*   mask = (const int*)d_in[2];
    const float* W0   = (const float*)d_in[3];
    const float* b0   = (const float*)d_in[4];
    const float* W1   = (const float*)d_in[5];
    const float* b1   = (const float*)d_in[6];
    const float* W2   = (const float*)d_in[7];
    const float* b2   = (const float*)d_in[8];

    short* ws = (short*)d_ws;

    prep_kernel<<<64, 256, 0, stream>>>(W0, W1, ws);
    fused_kernel<<<B_ / BPB, 256, 0, stream>>>(hist, tgt, mask, ws, b0, b1, W2, b2,
                                               (float*)d_out);
}

// Round 8
// 332.167 us; speedup vs baseline: 1.6746x; 1.0007x over previous
//
#include <hip/hip_runtime.h>
#include <hip/hip_bf16.h>

#define B_  2048
#define L_  200
#define D_  128
#define H0_ 80
#define H1_ 40
#define BPB 2              // batches per block -> grid 1024 = 4 blocks/CU
#define NTILE 13           // 16-row score tiles per batch (208 rows, 8 pad)

// ws layout (shorts): Bg[80][256] @0 | w1t[48][96] @20480 | w0p[128][84] @25088
#define WS_BG  0
#define WS_W1T 20480
#define WS_W0P 25088
#define WS_TOT 35840

typedef __attribute__((ext_vector_type(8))) short short8;
typedef __attribute__((ext_vector_type(4))) float floatx4;
typedef __attribute__((ext_vector_type(2))) float floatx2;

__device__ __forceinline__ short f2bf(float f) {
    unsigned u = __float_as_uint(f);
    u += 0x7fffu + ((u >> 16) & 1u);   // round-to-nearest-even
    return (short)(u >> 16);
}
__device__ __forceinline__ float bf2f(short s) {
    return __uint_as_float(((unsigned)(unsigned short)s) << 16);
}

// ---------------- prep: pure weight transform, one pass ---------------------
// feat@W0 = hist@(W0a+W0c) + (hist.*tgt)@W0d + [tgt@(W0b-W0c)+b0]
__global__ __launch_bounds__(256) void prep_kernel(
    const float* __restrict__ W0, const float* __restrict__ W1,
    short* __restrict__ ws)
{
    for (int i = blockIdx.x * 256 + threadIdx.x; i < WS_TOT; i += 64 * 256) {
        short v;
        if (i < WS_W1T) {                       // Bg[h][k]: k<128 W0a+W0c, k>=128 W0d
            int h = i >> 8, k = i & 255;
            float x = (k < 128) ? (W0[(size_t)k * H0_ + h] + W0[(size_t)(256 + k) * H0_ + h])
                                : W0[(size_t)(384 + (k - 128)) * H0_ + h];
            v = f2bf(x);
        } else if (i < WS_W0P) {                // w1t[n][k] 48x96, zero-padded
            int j = i - WS_W1T;
            int n = j / 96, k = j - n * 96;
            v = (n < H1_ && k < H0_) ? f2bf(W1[(size_t)k * H1_ + n]) : (short)0;
        } else {                                // w0p[d][h] 128x84 = bf16(W0b-W0c), padded
            int j = i - WS_W0P;
            int d = j / 84, h = j - d * 84;
            v = (h < H0_) ? f2bf(W0[(size_t)(128 + d) * H0_ + h] - W0[(size_t)(256 + d) * H0_ + h])
                          : (short)0;
        }
        ws[i] = v;
    }
}

// ---------------- fused: per-batch W0eff (LDS) GEMM + softmax + wsum --------
// W0eff[b][d][h] = Bg1[h][d] + tgt[b][d]*Bg2[h][d]   (layer-0 K=128)
// A-tile loads software-pipelined (next tile in flight during compute).
__global__ __launch_bounds__(256, 2) void fused_kernel(
    const float* __restrict__ hist, const float* __restrict__ tgt,
    const int* __restrict__ mask, const short* __restrict__ ws,
    const float* __restrict__ b0p, const float* __restrict__ b1,
    const float* __restrict__ W2, const float* __restrict__ b2,
    float* __restrict__ out)
{
    __shared__ __align__(16) short wbuf[10752];      // w0p[128][84] then W0eff[80][132]
    __shared__ __align__(16) short h0t[4][16][100];  // 12800 B; tail: pw[4][128]+attn_w[2][200] f32
    __shared__ float tgs4[BPB][D_];                  // 1024 B
    __shared__ float beffs[BPB][H0_];                // 640 B
    __shared__ float scores4[BPB][208];              // 1664 B
    // total 37632 B -> 4 blocks/CU; VGPR target 128 -> 16 waves/CU

    const int tid = threadIdx.x;
    const int wave = tid >> 6, lane = tid & 63;
    const int col = lane & 15, quad = lane >> 4;
    const int bbase = blockIdx.x * BPB;

    // ---- prologue: stage w0p + tgt rows, zero h0t k-tail, hoist w1 frags ----
    for (int i = tid; i < 1344; i += 256)                 // w0p: 10752 shorts
        *(short8*)(wbuf + i * 8) = *(const short8*)(ws + WS_W0P + i * 8);
    for (int i = tid; i < BPB * D_; i += 256)
        tgs4[i >> 7][i & 127] = tgt[(size_t)(bbase + (i >> 7)) * D_ + (i & 127)];
    if (tid < 128) {                                      // zero h0t cols 80..95
        int w = tid >> 5, row = (tid >> 1) & 15, c = 80 + (tid & 1) * 8;
        *(short8*)&h0t[w][row][c] = (short8)0;
    }
    short8 w1f[3][3];
    #pragma unroll
    for (int ks = 0; ks < 3; ++ks)
        #pragma unroll
        for (int nt = 0; nt < 3; ++nt)
            w1f[ks][nt] = *(const short8*)(ws + WS_W1T + (nt * 16 + col) * 96 + ks * 32 + quad * 8);
    float b1r[3], w2r[3];
    #pragma unroll
    for (int nt = 0; nt < 3; ++nt) {
        int h = nt * 16 + col;
        b1r[nt] = (h < H1_) ? b1[h] : 0.f;
        w2r[nt] = (h < H1_) ? W2[h] : 0.f;
    }
    const float b2v = b2[0];
    __syncthreads();

    // ---- beff: beff[bb][h] = b0[h] + tgt[bb] . (W0b-W0c)[:,h] ----
    if (tid < 160) {
        int bb = tid >= 80 ? 1 : 0, h = tid - bb * 80;
        float s = 0.f;
        #pragma unroll 8
        for (int d = 0; d < D_; ++d) s += tgs4[bb][d] * bf2f(wbuf[d * 84 + h]);
        beffs[bb][h] = b0p[h] + s;
    }
    __syncthreads();                                      // w0p region now free

    // ---- per-batch: build W0eff in LDS, then pipelined score tiles ----
    for (int bb = 0; bb < BPB; ++bb) {
        const int b = bbase + bb;
        int t = (wave + bb) & 3;                          // 13 tiles spread over 4 waves

        // issue first A-tile load BEFORE the W0eff build (latency hides under build)
        floatx4 A[8];
        {
            const int l = t * 16 + col;
            const int lc = (l < L_) ? l : (L_ - 1);
            const float* ap = hist + ((size_t)b * L_ + lc) * D_ + quad * 8;
            #pragma unroll
            for (int u = 0; u < 8; ++u)
                A[u] = *(const floatx4*)(ap + (u >> 1) * 32 + (u & 1) * 4);
        }

        for (int i = tid; i < 1280; i += 256) {           // W0eff: 80 rows x 16 chunks of 8
            int h = i >> 4, d0 = (i & 15) * 8;
            short8 wa = *(const short8*)(ws + WS_BG + h * 256 + d0);
            short8 wd = *(const short8*)(ws + WS_BG + h * 256 + 128 + d0);
            floatx4 t0 = *(const floatx4*)&tgs4[bb][d0];
            floatx4 t1 = *(const floatx4*)&tgs4[bb][d0 + 4];
            short8 o;
            #pragma unroll
            for (int j = 0; j < 4; ++j) o[j] = f2bf(bf2f(wa[j]) + t0[j] * bf2f(wd[j]));
            #pragma unroll
            for (int j = 4; j < 8; ++j) o[j] = f2bf(bf2f(wa[j]) + t1[j - 4] * bf2f(wd[j]));
            *(short8*)(wbuf + h * 132 + d0) = o;
        }
        __syncthreads();

        while (t < NTILE) {
            const int tn = t + 4;
            // prefetch next tile's A while computing this one
            floatx4 An[8];
            if (tn < NTILE) {
                const int l = tn * 16 + col;
                const int lc = (l < L_) ? l : (L_ - 1);
                const float* ap = hist + ((size_t)b * L_ + lc) * D_ + quad * 8;
                #pragma unroll
                for (int u = 0; u < 8; ++u)
                    An[u] = *(const floatx4*)(ap + (u >> 1) * 32 + (u & 1) * 4);
            }

            // pack A-frags (hist only; K=128)
            short8 ah[4];
            #pragma unroll
            for (int ks = 0; ks < 4; ++ks) {
                short8 h8;
                #pragma unroll
                for (int j = 0; j < 8; ++j) h8[j] = f2bf(A[2 * ks + (j >> 2)][j & 3]);
                ah[ks] = h8;
            }

            // layer 0: K=128 against per-batch W0eff (B-frags from LDS)
            floatx4 c0[5];
            #pragma unroll
            for (int nt = 0; nt < 5; ++nt) c0[nt] = (floatx4)0.f;
            #pragma unroll
            for (int ks = 0; ks < 4; ++ks)
                #pragma unroll
                for (int nt = 0; nt < 5; ++nt) {
                    short8 bfr = *(const short8*)(wbuf + (nt * 16 + col) * 132 + ks * 32 + quad * 8);
                    c0[nt] = __builtin_amdgcn_mfma_f32_16x16x32_bf16(ah[ks], bfr, c0[nt], 0, 0, 0);
                }

            // bias+relu -> wave-private h0 tile
            #pragma unroll
            for (int nt = 0; nt < 5; ++nt) {
                float be = beffs[bb][nt * 16 + col];
                #pragma unroll
                for (int r = 0; r < 4; ++r) {
                    float v = c0[nt][r] + be;
                    v = v > 0.f ? v : 0.f;
                    h0t[wave][quad * 4 + r][nt * 16 + col] = f2bf(v);
                }
            }

            // layer 1 (w1 frags in regs)
            floatx4 c1[3];
            #pragma unroll
            for (int nt = 0; nt < 3; ++nt) c1[nt] = (floatx4)0.f;
            #pragma unroll
            for (int ks = 0; ks < 3; ++ks) {
                short8 a1 = *(const short8*)&h0t[wave][col][ks * 32 + quad * 8];
                #pragma unroll
                for (int nt = 0; nt < 3; ++nt)
                    c1[nt] = __builtin_amdgcn_mfma_f32_16x16x32_bf16(a1, w1f[ks][nt], c1[nt], 0, 0, 0);
            }

            // layer 2 + 16-lane reduce -> LDS scores
            float s4[4] = {0.f, 0.f, 0.f, 0.f};
            #pragma unroll
            for (int nt = 0; nt < 3; ++nt)
                #pragma unroll
                for (int r = 0; r < 4; ++r) {
                    float v = c1[nt][r] + b1r[nt];
                    v = v > 0.f ? v : 0.f;
                    s4[r] += v * w2r[nt];
                }
            #pragma unroll
            for (int r = 0; r < 4; ++r) {
                s4[r] += __shfl_xor(s4[r], 1, 16);
                s4[r] += __shfl_xor(s4[r], 2, 16);
                s4[r] += __shfl_xor(s4[r], 4, 16);
                s4[r] += __shfl_xor(s4[r], 8, 16);
            }
            if (col == 0) {
                #pragma unroll
                for (int r = 0; r < 4; ++r)
                    scores4[bb][t * 16 + quad * 4 + r] = s4[r] + b2v;
            }

            if (tn < NTILE) {
                #pragma unroll
                for (int u = 0; u < 8; ++u) A[u] = An[u];
            }
            t = tn;
        }
        __syncthreads();                                  // scores done / W0eff free
    }

    // ---- tail: one batch per wave-pair, softmax in-wave, then wsum ----
    float* pw = (float*)&h0t[0][0][0];                    // [4][128]
    float* attn_w = pw + 4 * 128;                         // [2][200]
    {
        const int bb = wave >> 1, b = bbase + bb, half = wave & 1;
        float sc[4], e[4];
        float m = -3.0e38f;
        #pragma unroll
        for (int j = 0; j < 4; ++j) {
            int idx = lane + 64 * j;
            if (idx < L_) {
                float v = scores4[bb][idx];
                if (mask[(size_t)b * L_ + idx] == 0) v -= 1e9f;
                sc[j] = v;
                m = fmaxf(m, v);
            } else sc[j] = -3.0e38f;
        }
        #pragma unroll
        for (int off = 32; off >= 1; off >>= 1) m = fmaxf(m, __shfl_xor(m, off, 64));
        float s = 0.f;
        #pragma unroll
        for (int j = 0; j < 4; ++j) {
            int idx = lane + 64 * j;
            e[j] = (idx < L_) ? __expf(sc[j] - m) : 0.f;
            s += e[j];
        }
        #pragma unroll
        for (int off = 32; off >= 1; off >>= 1) s += __shfl_xor(s, off, 64);
        float inv = 1.0f / s;
        if (half == 0) {
            #pragma unroll
            for (int j = 0; j < 4; ++j) {
                int idx = lane + 64 * j;
                if (idx < L_) {
                    float av = e[j] * inv;
                    attn_w[bb * 200 + idx] = av;
                    out[(size_t)B_ * D_ + (size_t)b * L_ + idx] = av;
                }
            }
        }
    }
    __syncthreads();
    {
        const int bb = wave >> 1, b = bbase + bb, half = wave & 1;
        const int d2 = lane * 2;
        const float* hb = hist + ((size_t)b * L_ + half * 100) * D_ + d2;
        float a0 = 0.f, a1 = 0.f;
        #pragma unroll 25
        for (int l = 0; l < 100; ++l) {
            float w = attn_w[bb * 200 + half * 100 + l];
            floatx2 h2 = *(const floatx2*)(hb + (size_t)l * D_);
            a0 = fmaf(w, h2.x, a0);
            a1 = fmaf(w, h2.y, a1);
        }
        *(floatx2*)&pw[wave * 128 + d2] = floatx2{a0, a1};
    }
    __syncthreads();
    {
        int bp = tid >> 7, d = tid & 127;
        out[(size_t)(bbase + bp) * D_ + d] = pw[(bp * 2) * 128 + d] + pw[(bp * 2 + 1) * 128 + d];
    }
}

extern "C" void kernel_launch(void* const* d_in, const int* in_sizes, int n_in,
                              void* d_out, int out_size, void* d_ws, size_t ws_size,
                              hipStream_t stream) {
    const float* hist = (const float*)d_in[0];
    const float* tgt  = (const float*)d_in[1];
    const int*   mask = (const int*)d_in[2];
    const float* W0   = (const float*)d_in[3];
    const float* b0   = (const float*)d_in[4];
    const float* W1   = (const float*)d_in[5];
    const float* b1   = (const float*)d_in[6];
    const float* W2   = (const float*)d_in[7];
    const float* b2   = (const float*)d_in[8];

    short* ws = (short*)d_ws;

    prep_kernel<<<64, 256, 0, stream>>>(W0, W1, ws);
    fused_kernel<<<B_ / BPB, 256, 0, stream>>>(hist, tgt, mask, ws, b0, b1, W2, b2,
                                               (float*)d_out);
}

// Round 9
// 331.653 us; speedup vs baseline: 1.6772x; 1.0015x over previous
//
#include <hip/hip_runtime.h>
#include <hip/hip_bf16.h>

#define B_  2048
#define L_  200
#define D_  128
#define H0_ 80
#define H1_ 40
#define NTILE 13           // 16-row score tiles per batch (208 rows, 8 pad)

// ws layout (shorts): Bg[80][256] @0 | w1t[48][96] @20480 | w0p[128][84] @25088
#define WS_BG  0
#define WS_W1T 20480
#define WS_W0P 25088
#define WS_TOT 35840

typedef __attribute__((ext_vector_type(8))) short short8;
typedef __attribute__((ext_vector_type(4))) float floatx4;

__device__ __forceinline__ short f2bf(float f) {
    unsigned u = __float_as_uint(f);
    u += 0x7fffu + ((u >> 16) & 1u);   // round-to-nearest-even
    return (short)(u >> 16);
}
__device__ __forceinline__ float bf2f(short s) {
    return __uint_as_float(((unsigned)(unsigned short)s) << 16);
}

// ---------------- prep: pure weight transform, one pass ---------------------
// feat@W0 = hist@(W0a+W0c) + (hist.*tgt)@W0d + [tgt@(W0b-W0c)+b0]
__global__ __launch_bounds__(256) void prep_kernel(
    const float* __restrict__ W0, const float* __restrict__ W1,
    short* __restrict__ ws)
{
    for (int i = blockIdx.x * 256 + threadIdx.x; i < WS_TOT; i += 64 * 256) {
        short v;
        if (i < WS_W1T) {                       // Bg[h][k]: k<128 W0a+W0c, k>=128 W0d
            int h = i >> 8, k = i & 255;
            float x = (k < 128) ? (W0[(size_t)k * H0_ + h] + W0[(size_t)(256 + k) * H0_ + h])
                                : W0[(size_t)(384 + (k - 128)) * H0_ + h];
            v = f2bf(x);
        } else if (i < WS_W0P) {                // w1t[n][k] 48x96, zero-padded
            int j = i - WS_W1T;
            int n = j / 96, k = j - n * 96;
            v = (n < H1_ && k < H0_) ? f2bf(W1[(size_t)k * H1_ + n]) : (short)0;
        } else {                                // w0p[d][h] 128x84 = bf16(W0b-W0c), padded
            int j = i - WS_W0P;
            int d = j / 84, h = j - d * 84;
            v = (h < H0_) ? f2bf(W0[(size_t)(128 + d) * H0_ + h] - W0[(size_t)(256 + d) * H0_ + h])
                          : (short)0;
        }
        ws[i] = v;
    }
}

// ---------------- fused: one batch per block, W0eff (LDS) GEMM + tail -------
// W0eff[b][d][h] = Bg1[h][d] + tgt[b][d]*Bg2[h][d]   (layer-0 K=128)
// grid 2048; LDS 36.0 KB -> 4 blocks/CU; VGPR <=128 -> 16 waves/CU.
__global__ __launch_bounds__(256, 2) void fused_kernel(
    const float* __restrict__ hist, const float* __restrict__ tgt,
    const int* __restrict__ mask, const short* __restrict__ ws,
    const float* __restrict__ b0p, const float* __restrict__ b1,
    const float* __restrict__ W2, const float* __restrict__ b2,
    float* __restrict__ out)
{
    __shared__ __align__(16) short wbuf[10752];      // w0p[128][84] then W0eff[80][132]
    __shared__ __align__(16) short h0t[4][16][100];  // 12800 B; tail aliases pw[4][128] f32
    __shared__ float tgs[D_];                        // 512 B
    __shared__ float beffs[H0_];                     // 320 B
    __shared__ float scores[208];                    // 832 B; aliases beff partials; then attn_w
    __shared__ float red[8];
    // total 36000 B

    const int tid = threadIdx.x;
    const int wave = tid >> 6, lane = tid & 63;
    const int col = lane & 15, quad = lane >> 4;
    const int b = blockIdx.x;

    // ---- prologue: stage w0p + tgt, zero h0t k-tail, hoist w1 frags ----
    for (int i = tid; i < 1344; i += 256)                 // w0p: 10752 shorts
        *(short8*)(wbuf + i * 8) = *(const short8*)(ws + WS_W0P + i * 8);
    if (tid < D_) tgs[tid] = tgt[(size_t)b * D_ + tid];
    if (tid < 128) {                                      // zero h0t cols 80..95
        int w = tid >> 5, row = (tid >> 1) & 15, c = 80 + (tid & 1) * 8;
        *(short8*)&h0t[w][row][c] = (short8)0;
    }
    short8 w1f[3][3];
    #pragma unroll
    for (int ks = 0; ks < 3; ++ks)
        #pragma unroll
        for (int nt = 0; nt < 3; ++nt)
            w1f[ks][nt] = *(const short8*)(ws + WS_W1T + (nt * 16 + col) * 96 + ks * 32 + quad * 8);
    float b1r[3], w2r[3];
    #pragma unroll
    for (int nt = 0; nt < 3; ++nt) {
        int h = nt * 16 + col;
        b1r[nt] = (h < H1_) ? b1[h] : 0.f;
        w2r[nt] = (h < H1_) ? W2[h] : 0.f;
    }
    const float b2v = b2[0];
    __syncthreads();

    // ---- beff[h] = b0[h] + tgt . (W0b-W0c)[:,h], 2 d-segments ----
    float* red2 = &scores[0];                             // [2][80], freed before scores
    if (tid < 160) {
        int seg = tid / 80, h = tid - seg * 80;
        int d0 = seg * 64;
        float s = 0.f;
        #pragma unroll 8
        for (int d = d0; d < d0 + 64; ++d) s += tgs[d] * bf2f(wbuf[d * 84 + h]);
        red2[seg * 80 + h] = s;
    }
    __syncthreads();
    if (tid < H0_) beffs[tid] = b0p[tid] + red2[tid] + red2[80 + tid];
    __syncthreads();                                      // w0p region now free

    // ---- build W0eff in LDS ----
    for (int i = tid; i < 1280; i += 256) {               // 80 rows x 16 chunks of 8
        int h = i >> 4, d0 = (i & 15) * 8;
        short8 wa = *(const short8*)(ws + WS_BG + h * 256 + d0);
        short8 wd = *(const short8*)(ws + WS_BG + h * 256 + 128 + d0);
        floatx4 t0 = *(const floatx4*)&tgs[d0];
        floatx4 t1 = *(const floatx4*)&tgs[d0 + 4];
        short8 o;
        #pragma unroll
        for (int j = 0; j < 4; ++j) o[j] = f2bf(bf2f(wa[j]) + t0[j] * bf2f(wd[j]));
        #pragma unroll
        for (int j = 4; j < 8; ++j) o[j] = f2bf(bf2f(wa[j]) + t1[j - 4] * bf2f(wd[j]));
        *(short8*)(wbuf + h * 132 + d0) = o;
    }
    __syncthreads();

    // ---- score phase: 13 tiles over 4 waves ----
    for (int t = wave; t < NTILE; t += 4) {
        const int l = t * 16 + col;
        const int lc = (l < L_) ? l : (L_ - 1);           // clamp pad rows (masked later)
        const float* ap = hist + ((size_t)b * L_ + lc) * D_ + quad * 8;

        floatx4 A[8];
        #pragma unroll
        for (int u = 0; u < 8; ++u)
            A[u] = *(const floatx4*)(ap + (u >> 1) * 32 + (u & 1) * 4);

        short8 ah[4];
        #pragma unroll
        for (int ks = 0; ks < 4; ++ks) {
            short8 h8;
            #pragma unroll
            for (int j = 0; j < 8; ++j) h8[j] = f2bf(A[2 * ks + (j >> 2)][j & 3]);
            ah[ks] = h8;
        }

        // layer 0: K=128 against per-batch W0eff (B-frags from LDS)
        floatx4 c0[5];
        #pragma unroll
        for (int nt = 0; nt < 5; ++nt) c0[nt] = (floatx4)0.f;
        #pragma unroll
        for (int ks = 0; ks < 4; ++ks)
            #pragma unroll
            for (int nt = 0; nt < 5; ++nt) {
                short8 bfr = *(const short8*)(wbuf + (nt * 16 + col) * 132 + ks * 32 + quad * 8);
                c0[nt] = __builtin_amdgcn_mfma_f32_16x16x32_bf16(ah[ks], bfr, c0[nt], 0, 0, 0);
            }

        // bias+relu -> wave-private h0 tile
        #pragma unroll
        for (int nt = 0; nt < 5; ++nt) {
            float be = beffs[nt * 16 + col];
            #pragma unroll
            for (int r = 0; r < 4; ++r) {
                float v = c0[nt][r] + be;
                v = v > 0.f ? v : 0.f;
                h0t[wave][quad * 4 + r][nt * 16 + col] = f2bf(v);
            }
        }

        // layer 1 (w1 frags in regs)
        floatx4 c1[3];
        #pragma unroll
        for (int nt = 0; nt < 3; ++nt) c1[nt] = (floatx4)0.f;
        #pragma unroll
        for (int ks = 0; ks < 3; ++ks) {
            short8 a1 = *(const short8*)&h0t[wave][col][ks * 32 + quad * 8];
            #pragma unroll
            for (int nt = 0; nt < 3; ++nt)
                c1[nt] = __builtin_amdgcn_mfma_f32_16x16x32_bf16(a1, w1f[ks][nt], c1[nt], 0, 0, 0);
        }

        // layer 2 + 16-lane reduce -> LDS scores
        float s4[4] = {0.f, 0.f, 0.f, 0.f};
        #pragma unroll
        for (int nt = 0; nt < 3; ++nt)
            #pragma unroll
            for (int r = 0; r < 4; ++r) {
                float v = c1[nt][r] + b1r[nt];
                v = v > 0.f ? v : 0.f;
                s4[r] += v * w2r[nt];
            }
        #pragma unroll
        for (int r = 0; r < 4; ++r) {
            s4[r] += __shfl_xor(s4[r], 1, 16);
            s4[r] += __shfl_xor(s4[r], 2, 16);
            s4[r] += __shfl_xor(s4[r], 4, 16);
            s4[r] += __shfl_xor(s4[r], 8, 16);
        }
        if (col == 0) {
            #pragma unroll
            for (int r = 0; r < 4; ++r)
                scores[t * 16 + quad * 4 + r] = s4[r] + b2v;
        }
    }
    __syncthreads();

    // ---- softmax (block-wide, r2-proven pattern) ----
    float sc = -3.0e38f;
    if (tid < L_) {
        sc = scores[tid];
        if (mask[(size_t)b * L_ + tid] == 0) sc -= 1e9f;
    }
    float m = sc;
    #pragma unroll
    for (int off = 32; off >= 1; off >>= 1) m = fmaxf(m, __shfl_xor(m, off, 64));
    if (lane == 0) red[wave] = m;
    __syncthreads();
    m = fmaxf(fmaxf(red[0], red[1]), fmaxf(red[2], red[3]));
    float e = (tid < L_) ? __expf(sc - m) : 0.f;
    float s = e;
    #pragma unroll
    for (int off = 32; off >= 1; off >>= 1) s += __shfl_xor(s, off, 64);
    if (lane == 0) red[4 + wave] = s;
    __syncthreads();
    s = red[4] + red[5] + red[6] + red[7];
    float av = e * (1.0f / s);
    if (tid < L_) {
        scores[tid] = av;                                 // reuse as attn weights
        out[(size_t)B_ * D_ + (size_t)b * L_ + tid] = av;
    }
    __syncthreads();

    // ---- weighted sum: 4 waves x 50 rows, 2 rows/iter (float4/lane) ----
    float* pw = (float*)&h0t[0][0][0];                    // [4][128]
    {
        const int rsel = lane >> 5;                       // 0/1: which of the row pair
        const int d0 = (lane & 31) * 4;
        const int rbase = wave * 50;
        const float* hb = hist + ((size_t)b * L_ + rbase + rsel) * D_ + d0;
        floatx4 acc = (floatx4)0.f;
        #pragma unroll 25
        for (int i = 0; i < 25; ++i) {
            float w = scores[rbase + 2 * i + rsel];
            floatx4 h4 = *(const floatx4*)(hb + (size_t)(2 * i) * D_);
            acc.x = fmaf(w, h4.x, acc.x);
            acc.y = fmaf(w, h4.y, acc.y);
            acc.z = fmaf(w, h4.z, acc.z);
            acc.w = fmaf(w, h4.w, acc.w);
        }
        acc.x += __shfl_xor(acc.x, 32, 64);
        acc.y += __shfl_xor(acc.y, 32, 64);
        acc.z += __shfl_xor(acc.z, 32, 64);
        acc.w += __shfl_xor(acc.w, 32, 64);
        if (rsel == 0) *(floatx4*)&pw[wave * 128 + d0] = acc;
    }
    __syncthreads();
    if (tid < D_)
        out[(size_t)b * D_ + tid] = (pw[tid] + pw[128 + tid]) + (pw[256 + tid] + pw[384 + tid]);
}

extern "C" void kernel_launch(void* const* d_in, const int* in_sizes, int n_in,
                              void* d_out, int out_size, void* d_ws, size_t ws_size,
                              hipStream_t stream) {
    const float* hist = (const float*)d_in[0];
    const float* tgt  = (const float*)d_in[1];
    const int*   mask = (const int*)d_in[2];
    const float* W0   = (const float*)d_in[3];
    const float* b0   = (const float*)d_in[4];
    const float* W1   = (const float*)d_in[5];
    const float* b1   = (const float*)d_in[6];
    const float* W2   = (const float*)d_in[7];
    const float* b2   = (const float*)d_in[8];

    short* ws = (short*)d_ws;

    prep_kernel<<<64, 256, 0, stream>>>(W0, W1, ws);
    fused_kernel<<<B_, 256, 0, stream>>>(hist, tgt, mask, ws, b0, b1, W2, b2,
                                         (float*)d_out);
}